// Round 11
// baseline (285.925 us; speedup 1.0000x reference)
//
#include <hip/hip_runtime.h>
#include <hip/hip_fp16.h>
#include <stdint.h>

#define NN 100000
#define NE 1250000
#define DD 64
#define NL 4

#define NPART3 256           // partitions; one WG owns one partition in fillD
#define PSIZE3 391           // nodes per partition (256*391 = 100096 >= NN)
#define TILE4 1024           // int4s per radix tile = 4096 edges
#define NTB ((NE / 4 + TILE4 - 1) / TILE4)        // 306 tiles
#define SCANA_N (NPART3 * NTB)                    // 78336
#define SRCBITS 17           // src < 100000 < 2^17; dlocal < 391 < 2^9
#define CASTB (NN * DD / 4 / 256)                 // 6250 cast blocks

#define MB2 64               // nodes per MFMA layer block
#define L2BLOCKS ((NN + MB2 - 1) / MB2)   // 1563
#define APAD 136             // halfs per A/Bt LDS row
#define CPADH 72             // halfs per C row
#define CPADF 68             // floats per C row

typedef _Float16 half8 __attribute__((ext_vector_type(8)));
typedef _Float16 half2v __attribute__((ext_vector_type(2)));
typedef float floatx4 __attribute__((ext_vector_type(4)));
typedef int intx4 __attribute__((ext_vector_type(4)));

__device__ __forceinline__ unsigned f2h2(float a, float b) {
    __half2 h = __floats2half2_rn(a, b);
    return *reinterpret_cast<unsigned*>(&h);
}
// packed fp16 max on raw bits (maps to v_pk_max_f16)
__device__ __forceinline__ unsigned umax2(unsigned a, unsigned b) {
    half2v x = *reinterpret_cast<half2v*>(&a);
    half2v y = *reinterpret_cast<half2v*>(&b);
    half2v r = __builtin_elementwise_max(x, y);
    return *reinterpret_cast<unsigned*>(&r);
}
__device__ __forceinline__ void umax4(uint4& a, uint4 u) {
    a.x = umax2(a.x, u.x); a.y = umax2(a.y, u.y);
    a.z = umax2(a.z, u.z); a.w = umax2(a.w, u.w);
}

// ---------------- fused: radix count (blocks 0..NTB-1) + fp32->fp16 cast (rest) ----------------
// Independent work, disjoint outputs; fusing removes one dispatch boundary.
// Block 0 also re-zeroes the scanP done counter (graph-replay safe).
__global__ __launch_bounds__(256) void pre1_kernel(const float* __restrict__ x,
                                                   __half* __restrict__ hh,
                                                   const int* __restrict__ dst,
                                                   int* __restrict__ blockcnt,
                                                   int* __restrict__ done) {
    int tid = threadIdx.x;
    int b = blockIdx.x;
    if (b < NTB) {
        __shared__ int cnt[NPART3];
        if (b == 0 && tid == 0) *done = 0;
        cnt[tid] = 0;
        __syncthreads();
        #pragma unroll
        for (int r = 0; r < 4; ++r) {
            int i4 = b * TILE4 + r * 256 + tid;
            if (i4 < NE / 4) {
                intx4 d = __builtin_nontemporal_load(&((const intx4*)dst)[i4]);
                atomicAdd(&cnt[(unsigned)d.x / PSIZE3], 1);
                atomicAdd(&cnt[(unsigned)d.y / PSIZE3], 1);
                atomicAdd(&cnt[(unsigned)d.z / PSIZE3], 1);
                atomicAdd(&cnt[(unsigned)d.w / PSIZE3], 1);
            }
        }
        __syncthreads();
        blockcnt[tid * NTB + b] = cnt[tid];
    } else {
        int i = (b - NTB) * 256 + tid;
        float4 v = ((const float4*)x)[i];
        uint2 u;
        u.x = f2h2(v.x, v.y);
        u.y = f2h2(v.z, v.w);
        ((uint2*)hh)[i] = u;
    }
}

// ---------------- fused two-level scan ----------------
// Each WG exclusive-scans its own 306-tile row and writes the row total; the
// LAST WG to finish (device-scope done counter + threadfence handoff) then
// exclusive-scans the 256 row totals in place (rowsum -> rowoff).
__global__ __launch_bounds__(512) void scanP_kernel(int* __restrict__ blockcnt,
                                                    int* __restrict__ rowsum,
                                                    int* __restrict__ done) {
    __shared__ int sm[512];
    __shared__ int lastFlag;
    int p = blockIdx.x;
    int tid = threadIdx.x;
    int v = (tid < NTB) ? blockcnt[p * NTB + tid] : 0;
    sm[tid] = v;
    __syncthreads();
    for (int off = 1; off < 512; off <<= 1) {
        int t = (tid >= off) ? sm[tid - off] : 0;
        __syncthreads();
        sm[tid] += t;
        __syncthreads();
    }
    if (tid < NTB) blockcnt[p * NTB + tid] = sm[tid] - v;   // exclusive in-row
    if (tid == 511) rowsum[p] = sm[511];                    // row total
    __threadfence();                                        // publish rowsum[p]
    __syncthreads();
    if (tid == 0) lastFlag = (atomicAdd(done, 1) == NPART3 - 1);
    __syncthreads();
    if (!lastFlag) return;
    __threadfence();                                        // acquire all rowsum writes
    int v2 = (tid < NPART3) ? rowsum[tid] : 0;
    sm[tid] = v2;
    __syncthreads();
    for (int off = 1; off < NPART3; off <<= 1) {
        int t = (tid >= off) ? sm[tid - off] : 0;
        __syncthreads();
        sm[tid] += t;
        __syncthreads();
    }
    if (tid < NPART3) rowsum[tid] = sm[tid] - v2;           // rowoff
}

// scatter packed (dlocal<<17 | src) into bucket order — one store per edge
__global__ __launch_bounds__(256) void scatterA_kernel(const int* __restrict__ src,
                                                       const int* __restrict__ dst,
                                                       const int* __restrict__ blockcnt,
                                                       const int* __restrict__ rowoff,
                                                       int* __restrict__ ebufP) {
    __shared__ int cur[NPART3];
    int tid = threadIdx.x;
    int b = blockIdx.x;
    cur[tid] = rowoff[tid] + blockcnt[tid * NTB + b];
    __syncthreads();
    #pragma unroll
    for (int r = 0; r < 4; ++r) {
        int i4 = b * TILE4 + r * 256 + tid;
        if (i4 < NE / 4) {
            intx4 d = __builtin_nontemporal_load(&((const intx4*)dst)[i4]);
            intx4 s = __builtin_nontemporal_load(&((const intx4*)src)[i4]);
            int part, p;
            part = (unsigned)d.x / PSIZE3; p = atomicAdd(&cur[part], 1);
            ebufP[p] = ((d.x - part * PSIZE3) << SRCBITS) | s.x;
            part = (unsigned)d.y / PSIZE3; p = atomicAdd(&cur[part], 1);
            ebufP[p] = ((d.y - part * PSIZE3) << SRCBITS) | s.y;
            part = (unsigned)d.z / PSIZE3; p = atomicAdd(&cur[part], 1);
            ebufP[p] = ((d.z - part * PSIZE3) << SRCBITS) | s.z;
            part = (unsigned)d.w / PSIZE3; p = atomicAdd(&cur[part], 1);
            ebufP[p] = ((d.w - part * PSIZE3) << SRCBITS) | s.w;
        }
    }
}

// ---- one WG per partition: LDS hist -> in-WG scan -> row_start + csr ----
__global__ __launch_bounds__(1024) void fillD_kernel(const int* __restrict__ ebufP,
                                                     const int* __restrict__ rowoff,
                                                     int* __restrict__ row_start,
                                                     int* __restrict__ csr) {
    __shared__ int cnt[PSIZE3];
    __shared__ int localstart[PSIZE3];
    __shared__ int partial[1024];
    int part = blockIdx.x;
    int tid = threadIdx.x;
    int nbase = part * PSIZE3;
    int base = rowoff[part];
    int hi = (part < NPART3 - 1) ? rowoff[part + 1] : NE;

    if (tid < PSIZE3) cnt[tid] = 0;
    __syncthreads();

    for (int i = base + tid; i < hi; i += 1024)
        atomicAdd(&cnt[(unsigned)ebufP[i] >> SRCBITS], 1);
    __syncthreads();

    int e0 = (tid < PSIZE3) ? cnt[tid] : 0;
    int s = e0;
    partial[tid] = s;
    __syncthreads();
    for (int off = 1; off < 1024; off <<= 1) {
        int v = (tid >= off) ? partial[tid - off] : 0;
        __syncthreads();
        partial[tid] += v;
        __syncthreads();
    }
    int run = partial[tid] - s;
    if (tid < PSIZE3) localstart[tid] = run;
    __syncthreads();

    int nmax = NN - nbase; if (nmax > PSIZE3) nmax = PSIZE3;
    if (tid < nmax) row_start[nbase + tid] = base + localstart[tid];
    if (part == NPART3 - 1 && tid == 0) row_start[NN] = NE;

    if (tid < PSIZE3) cnt[tid] = 0;
    __syncthreads();

    for (int i = base + tid; i < hi; i += 1024) {
        int p = ebufP[i];
        int dl = (unsigned)p >> SRCBITS;
        int local = atomicAdd(&cnt[dl], 1);
        csr[base + localstart[dl] + local] = p & ((1 << SRCBITS) - 1);
    }
}

// ---------------- per-layer gather-max: TRANSPOSED lanes, zero reduce (r6 best) ----------------
// lane = (node_local 0..7)*8 + chunk 0..7: each lane owns one 16B column chunk of
// one node and serially maxes over ALL its neighbors. No cross-lane reduce at all.
// One load instruction per iteration covers 8 full 128B rows (8 edges). csr
// indices consumed 8-at-a-time with a clamped prefetch of the next block (hides
// index-load latency under the gathers). Clamped duplicate slots are L1 hits.
// NOTE (r7-r10): class-scheduling, nt-hints, predication, and 16-deep batching
// all regressed vs this plain form — it is at the latency x concurrency floor.
__global__ __launch_bounds__(256, 6) void agg_kernel(const __half* __restrict__ hh,
                                                     const int* __restrict__ row_start,
                                                     const int* __restrict__ csr,
                                                     __half* __restrict__ aggh) {
    int tid = threadIdx.x;
    int wv = tid >> 6;
    int lane = tid & 63;
    int nl = lane >> 3;             // node_local 0..7
    int l8 = lane & 7;              // column chunk 0..7
    int c8 = l8 * 8;                // halfs offset of this lane's 16B chunk
    int nb = blockIdx.x * 32 + wv * 8;   // NN = 3125*32 exactly

    // row_start for nodes nb..nb+8 via one coalesced load + shuffles
    int rsl = row_start[nb + ((lane < 9) ? lane : 8)];
    int base = __shfl(rsl, nl, 64);
    int cnt  = __shfl(rsl, nl + 1, 64) - base;
    int cl   = max(cnt - 1, 0);
    int bclamp = min(base, NE - 1);

    // wave-wide max degree (cnt uniform within each 8-lane group)
    int km = cnt;
    km = max(km, __shfl_xor(km, 8, 64));
    km = max(km, __shfl_xor(km, 16, 64));
    km = max(km, __shfl_xor(km, 32, 64));

    const uint4 NI4 = make_uint4(0xFC00FC00u, 0xFC00FC00u, 0xFC00FC00u, 0xFC00FC00u);
    uint4 acc = NI4;
    int lsrc = lane & 56;           // node_local*8: shfl source base

    // preload first index block (8 indices per node, clamped)
    int idx = csr[bclamp + min(l8, cl)];
    for (int k0 = 0; k0 < km; k0 += 8) {
        // prefetch next block (clamped -> always safe, overlaps with gathers)
        int nidx = csr[bclamp + min(k0 + 8 + l8, cl)];
        #pragma unroll
        for (int j = 0; j < 8; ++j) {
            int srcv = __shfl(idx, lsrc + j, 64);
            uint4 u = *(const uint4*)&hh[(unsigned)srcv * DD + c8];
            umax4(acc, u);
        }
        idx = nidx;
    }

    if (cnt <= 0) acc = make_uint4(0, 0, 0, 0);
    // fully coalesced: 64 lanes = 8 complete rows (1 KB)
    *(uint4*)&aggh[(size_t)(nb + nl) * DD + c8] = acc;
}

// ---------------- dense update via MFMA ----------------
__global__ __launch_bounds__(256, 4) void layer_mfma_kernel(
        const __half* __restrict__ aggh,
        __half* __restrict__ hh,
        float* __restrict__ hout,
        const float* __restrict__ Wl,
        const float* __restrict__ bl,
        const float* __restrict__ Wr,
        int last) {
    __shared__ char smem[2 * MB2 * APAD * 2];   // 34816 B, reused by epilogue
    _Float16* a_s  = (_Float16*)smem;                          // [64][APAD]
    _Float16* bt_s = (_Float16*)(smem + MB2 * APAD * 2);       // [64][APAD], n-major

    int tid = threadIdx.x;
    int lane = tid & 63;
    int w = tid >> 6;
    int node0 = blockIdx.x * MB2;

    #pragma unroll
    for (int i = 0; i < 4; ++i) {
        int idx = i * 256 + tid;          // uint4 id, 1024 total
        int r = idx >> 4;
        int c4 = idx & 15;
        int node = node0 + r; if (node > NN - 1) node = NN - 1;
        const __half* srcp = (c4 < 8) ? (aggh + (size_t)node * DD + c4 * 8)
                                      : (hh + (size_t)node * DD + (c4 - 8) * 8);
        uint4 v = *(const uint4*)srcp;
        *(uint4*)&a_s[r * APAD + c4 * 8] = v;
    }
    {
        int n = tid & 63;
        int kb = tid >> 6;
        #pragma unroll
        for (int kk = 0; kk < 32; ++kk) {
            int k = kb * 32 + kk;
            float wv = (k < 64) ? Wl[k * DD + n] : Wr[(k - 64) * DD + n];
            bt_s[n * APAD + k] = (_Float16)wv;
        }
    }
    __syncthreads();

    floatx4 acc[4];
    #pragma unroll
    for (int nt = 0; nt < 4; ++nt) acc[nt] = (floatx4){0.f, 0.f, 0.f, 0.f};
    int m = lane & 15;
    int q = lane >> 4;

    #pragma unroll
    for (int ks = 0; ks < 4; ++ks) {
        half8 af = *(half8*)&a_s[(w * 16 + m) * APAD + q * 8 + ks * 32];
        #pragma unroll
        for (int nt = 0; nt < 4; ++nt) {
            half8 bf = *(half8*)&bt_s[(nt * 16 + m) * APAD + q * 8 + ks * 32];
            acc[nt] = __builtin_amdgcn_mfma_f32_16x16x32_f16(af, bf, acc[nt], 0, 0, 0);
        }
    }
    __syncthreads();

    _Float16* ch = (_Float16*)smem;                      // [64][CPADH]
    float*    cf = (float*)(smem + MB2 * CPADH * 2);     // [64][CPADF]

    #pragma unroll
    for (int nt = 0; nt < 4; ++nt) {
        int col = nt * 16 + m;
        float b = bl[col];
        #pragma unroll
        for (int r = 0; r < 4; ++r) {
            int rowl = w * 16 + q * 4 + r;
            float o = fmaxf(acc[nt][r] + b, 0.0f);
            if (last) cf[rowl * CPADF + col] = o;
            else      ch[rowl * CPADH + col] = (_Float16)o;
        }
    }
    __syncthreads();

    if (!last) {
        #pragma unroll
        for (int i = 0; i < 2; ++i) {
            int idx = i * 256 + tid;          // 512 uint4s
            int r = idx >> 3;
            int c4 = idx & 7;
            int node = node0 + r;
            if (node < NN) {
                uint4 v = *(uint4*)&ch[r * CPADH + c4 * 8];
                *(uint4*)&hh[(size_t)node * DD + c4 * 8] = v;
            }
        }
    } else {
        #pragma unroll
        for (int i = 0; i < 4; ++i) {
            int idx = i * 256 + tid;      // 1024 float4s
            int r = idx >> 4;
            int c4 = idx & 15;
            int node = node0 + r;
            if (node < NN) {
                float4 v = *(float4*)&cf[r * CPADF + c4 * 4];
                *(float4*)&hout[(size_t)node * DD + c4 * 4] = v;
            }
        }
    }
}

extern "C" void kernel_launch(void* const* d_in, const int* in_sizes, int n_in,
                              void* d_out, int out_size, void* d_ws, size_t ws_size,
                              hipStream_t stream) {
    const float* x  = (const float*)d_in[0];
    const int*   ei = (const int*)d_in[1];
    const float* Wl = (const float*)d_in[2];
    const float* bl = (const float*)d_in[3];
    const float* Wr = (const float*)d_in[4];
    float* h = (float*)d_out;

    const int* src = ei;
    const int* dst = ei + NE;

    char* ws = (char*)d_ws;
    __half* aggh     = (__half*)ws;  ws += (size_t)NN * DD * sizeof(__half);  // 12.8 MB
    __half* hh       = (__half*)ws;  ws += (size_t)NN * DD * sizeof(__half);  // 12.8 MB
    int* row_start   = (int*)ws;     ws += (size_t)(NN + 16) * sizeof(int);
    int* blockcnt    = (int*)ws;     ws += (size_t)(SCANA_N + 16) * sizeof(int);
    int* rowsum      = (int*)ws;     ws += (size_t)(NPART3 + 16) * sizeof(int);
    int* done        = (int*)ws;     ws += 16 * sizeof(int);
    int* csr         = (int*)ws;                                              // 5 MB

    // packed edge bucket reuses the aggh region (dead until first agg_kernel)
    int* ebufP = (int*)aggh;                     // NE ints = 5 MB <= 12.8 MB

    pre1_kernel<<<NTB + CASTB, 256, 0, stream>>>(x, hh, dst, blockcnt, done);
    scanP_kernel<<<NPART3, 512, 0, stream>>>(blockcnt, rowsum, done);
    scatterA_kernel<<<NTB, 256, 0, stream>>>(src, dst, blockcnt, rowsum, ebufP);
    fillD_kernel<<<NPART3, 1024, 0, stream>>>(ebufP, rowsum, row_start, csr);

    for (int l = 0; l < NL; ++l) {
        agg_kernel<<<NN / 32, 256, 0, stream>>>(hh, row_start, csr, aggh);
        layer_mfma_kernel<<<L2BLOCKS, 256, 0, stream>>>(
            aggh, hh, h, Wl + (size_t)l * DD * DD, bl + (size_t)l * DD, Wr + (size_t)l * DD * DD,
            (l == NL - 1) ? 1 : 0);
    }
}

// Round 12
// 256.195 us; speedup vs baseline: 1.1160x; 1.1160x over previous
//
#include <hip/hip_runtime.h>
#include <hip/hip_fp16.h>
#include <stdint.h>

#define NN 100000
#define NE 1250000
#define DD 64
#define NL 4

#define NPART3 256           // partitions; one WG owns one partition in fillD
#define PSIZE3 391           // nodes per partition (256*391 = 100096 >= NN)
#define TILE4 1024           // int4s per radix tile = 4096 edges
#define NTB ((NE / 4 + TILE4 - 1) / TILE4)        // 306 tiles
#define SCANA_N (NPART3 * NTB)                    // 78336
#define SRCBITS 17           // src < 100000 < 2^17; dlocal < 391 < 2^9

#define MB2 64               // nodes per MFMA layer block
#define L2BLOCKS ((NN + MB2 - 1) / MB2)   // 1563
#define APAD 136             // halfs per A/Bt LDS row
#define CPADH 72             // halfs per C row
#define CPADF 68             // floats per C row

typedef _Float16 half8 __attribute__((ext_vector_type(8)));
typedef _Float16 half2v __attribute__((ext_vector_type(2)));
typedef float floatx4 __attribute__((ext_vector_type(4)));
typedef int intx4 __attribute__((ext_vector_type(4)));

__device__ __forceinline__ unsigned f2h2(float a, float b) {
    __half2 h = __floats2half2_rn(a, b);
    return *reinterpret_cast<unsigned*>(&h);
}
// packed fp16 max on raw bits (maps to v_pk_max_f16)
__device__ __forceinline__ unsigned umax2(unsigned a, unsigned b) {
    half2v x = *reinterpret_cast<half2v*>(&a);
    half2v y = *reinterpret_cast<half2v*>(&b);
    half2v r = __builtin_elementwise_max(x, y);
    return *reinterpret_cast<unsigned*>(&r);
}
__device__ __forceinline__ void umax4(uint4& a, uint4 u) {
    a.x = umax2(a.x, u.x); a.y = umax2(a.y, u.y);
    a.z = umax2(a.z, u.z); a.w = umax2(a.w, u.w);
}

// ---- x (fp32) -> hh (fp16) ----
__global__ __launch_bounds__(256) void cast_kernel(const float* __restrict__ x,
                                                   __half* __restrict__ hh) {
    int i = blockIdx.x * 256 + threadIdx.x;
    float4 v = ((const float4*)x)[i];
    uint2 u;
    u.x = f2h2(v.x, v.y);
    u.y = f2h2(v.z, v.w);
    ((uint2*)hh)[i] = u;
}

// ---------------- radix bucketing: edges -> 256 dst-partition buckets ----------------
__global__ __launch_bounds__(256) void countA_kernel(const int* __restrict__ dst,
                                                     int* __restrict__ blockcnt) {
    __shared__ int cnt[NPART3];
    int tid = threadIdx.x;
    cnt[tid] = 0;
    __syncthreads();
    int b = blockIdx.x;
    #pragma unroll
    for (int r = 0; r < 4; ++r) {
        int i4 = b * TILE4 + r * 256 + tid;
        if (i4 < NE / 4) {
            intx4 d = __builtin_nontemporal_load(&((const intx4*)dst)[i4]);
            atomicAdd(&cnt[(unsigned)d.x / PSIZE3], 1);
            atomicAdd(&cnt[(unsigned)d.y / PSIZE3], 1);
            atomicAdd(&cnt[(unsigned)d.z / PSIZE3], 1);
            atomicAdd(&cnt[(unsigned)d.w / PSIZE3], 1);
        }
    }
    __syncthreads();
    blockcnt[tid * NTB + b] = cnt[tid];
}

// ---- parallel scan, stage 1: each WG exclusive-scans its own 306-tile row ----
__global__ __launch_bounds__(512) void scanP1_kernel(int* __restrict__ blockcnt,
                                                     int* __restrict__ rowsum) {
    __shared__ int sm[512];
    int p = blockIdx.x;
    int tid = threadIdx.x;
    int v = (tid < NTB) ? blockcnt[p * NTB + tid] : 0;
    sm[tid] = v;
    __syncthreads();
    for (int off = 1; off < 512; off <<= 1) {
        int t = (tid >= off) ? sm[tid - off] : 0;
        __syncthreads();
        sm[tid] += t;
        __syncthreads();
    }
    if (tid < NTB) blockcnt[p * NTB + tid] = sm[tid] - v;   // exclusive in-row
    if (tid == 511) rowsum[p] = sm[511];                    // row total
}

// ---- parallel scan, stage 2: exclusive scan of the 256 row totals (in place) ----
__global__ __launch_bounds__(256) void scanP2_kernel(int* __restrict__ rowsum) {
    __shared__ int sm[256];
    int tid = threadIdx.x;
    int v = rowsum[tid];
    sm[tid] = v;
    __syncthreads();
    for (int off = 1; off < 256; off <<= 1) {
        int t = (tid >= off) ? sm[tid - off] : 0;
        __syncthreads();
        sm[tid] += t;
        __syncthreads();
    }
    rowsum[tid] = sm[tid] - v;    // rowoff: global start of partition tid
}

// scatter packed (dlocal<<17 | src) into bucket order — one store per edge
__global__ __launch_bounds__(256) void scatterA_kernel(const int* __restrict__ src,
                                                       const int* __restrict__ dst,
                                                       const int* __restrict__ blockcnt,
                                                       const int* __restrict__ rowoff,
                                                       int* __restrict__ ebufP) {
    __shared__ int cur[NPART3];
    int tid = threadIdx.x;
    int b = blockIdx.x;
    cur[tid] = rowoff[tid] + blockcnt[tid * NTB + b];
    __syncthreads();
    #pragma unroll
    for (int r = 0; r < 4; ++r) {
        int i4 = b * TILE4 + r * 256 + tid;
        if (i4 < NE / 4) {
            intx4 d = __builtin_nontemporal_load(&((const intx4*)dst)[i4]);
            intx4 s = __builtin_nontemporal_load(&((const intx4*)src)[i4]);
            int part, p;
            part = (unsigned)d.x / PSIZE3; p = atomicAdd(&cur[part], 1);
            ebufP[p] = ((d.x - part * PSIZE3) << SRCBITS) | s.x;
            part = (unsigned)d.y / PSIZE3; p = atomicAdd(&cur[part], 1);
            ebufP[p] = ((d.y - part * PSIZE3) << SRCBITS) | s.y;
            part = (unsigned)d.z / PSIZE3; p = atomicAdd(&cur[part], 1);
            ebufP[p] = ((d.z - part * PSIZE3) << SRCBITS) | s.z;
            part = (unsigned)d.w / PSIZE3; p = atomicAdd(&cur[part], 1);
            ebufP[p] = ((d.w - part * PSIZE3) << SRCBITS) | s.w;
        }
    }
}

// ---- one WG per partition: LDS hist -> in-WG scan -> row_start + csr ----
__global__ __launch_bounds__(1024) void fillD_kernel(const int* __restrict__ ebufP,
                                                     const int* __restrict__ rowoff,
                                                     int* __restrict__ row_start,
                                                     int* __restrict__ csr) {
    __shared__ int cnt[PSIZE3];
    __shared__ int localstart[PSIZE3];
    __shared__ int partial[1024];
    int part = blockIdx.x;
    int tid = threadIdx.x;
    int nbase = part * PSIZE3;
    int base = rowoff[part];
    int hi = (part < NPART3 - 1) ? rowoff[part + 1] : NE;

    if (tid < PSIZE3) cnt[tid] = 0;
    __syncthreads();

    for (int i = base + tid; i < hi; i += 1024)
        atomicAdd(&cnt[(unsigned)ebufP[i] >> SRCBITS], 1);
    __syncthreads();

    int e0 = (tid < PSIZE3) ? cnt[tid] : 0;
    int s = e0;
    partial[tid] = s;
    __syncthreads();
    for (int off = 1; off < 1024; off <<= 1) {
        int v = (tid >= off) ? partial[tid - off] : 0;
        __syncthreads();
        partial[tid] += v;
        __syncthreads();
    }
    int run = partial[tid] - s;
    if (tid < PSIZE3) localstart[tid] = run;
    __syncthreads();

    int nmax = NN - nbase; if (nmax > PSIZE3) nmax = PSIZE3;
    if (tid < nmax) row_start[nbase + tid] = base + localstart[tid];
    if (part == NPART3 - 1 && tid == 0) row_start[NN] = NE;

    if (tid < PSIZE3) cnt[tid] = 0;
    __syncthreads();

    for (int i = base + tid; i < hi; i += 1024) {
        int p = ebufP[i];
        int dl = (unsigned)p >> SRCBITS;
        int local = atomicAdd(&cnt[dl], 1);
        csr[base + localstart[dl] + local] = p & ((1 << SRCBITS) - 1);
    }
}

// ---------------- per-layer gather-max: TRANSPOSED lanes, zero reduce ----------------
// lane = (node_local 0..7)*8 + chunk 0..7: each lane owns one 16B column chunk of
// one node and serially maxes over ALL its neighbors. No cross-lane reduce at all.
// One load instruction per iteration covers 8 full 128B rows (8 edges). csr
// indices consumed 8-at-a-time with a clamped prefetch of the next block (hides
// index-load latency under the gathers). Clamped duplicate slots are L1 hits.
// NOTE (r7-r11): class-scheduling, nt-hints, predication, 16-deep batching and
// dispatch fusion all regressed vs this plain form — latency x concurrency floor.
__global__ __launch_bounds__(256, 6) void agg_kernel(const __half* __restrict__ hh,
                                                     const int* __restrict__ row_start,
                                                     const int* __restrict__ csr,
                                                     __half* __restrict__ aggh) {
    int tid = threadIdx.x;
    int wv = tid >> 6;
    int lane = tid & 63;
    int nl = lane >> 3;             // node_local 0..7
    int l8 = lane & 7;              // column chunk 0..7
    int c8 = l8 * 8;                // halfs offset of this lane's 16B chunk
    int nb = blockIdx.x * 32 + wv * 8;   // NN = 3125*32 exactly

    // row_start for nodes nb..nb+8 via one coalesced load + shuffles
    int rsl = row_start[nb + ((lane < 9) ? lane : 8)];
    int base = __shfl(rsl, nl, 64);
    int cnt  = __shfl(rsl, nl + 1, 64) - base;
    int cl   = max(cnt - 1, 0);
    int bclamp = min(base, NE - 1);

    // wave-wide max degree (cnt uniform within each 8-lane group)
    int km = cnt;
    km = max(km, __shfl_xor(km, 8, 64));
    km = max(km, __shfl_xor(km, 16, 64));
    km = max(km, __shfl_xor(km, 32, 64));

    const uint4 NI4 = make_uint4(0xFC00FC00u, 0xFC00FC00u, 0xFC00FC00u, 0xFC00FC00u);
    uint4 acc = NI4;
    int lsrc = lane & 56;           // node_local*8: shfl source base

    // preload first index block (8 indices per node, clamped)
    int idx = csr[bclamp + min(l8, cl)];
    for (int k0 = 0; k0 < km; k0 += 8) {
        // prefetch next block (clamped -> always safe, overlaps with gathers)
        int nidx = csr[bclamp + min(k0 + 8 + l8, cl)];
        #pragma unroll
        for (int j = 0; j < 8; ++j) {
            int srcv = __shfl(idx, lsrc + j, 64);
            uint4 u = *(const uint4*)&hh[(unsigned)srcv * DD + c8];
            umax4(acc, u);
        }
        idx = nidx;
    }

    if (cnt <= 0) acc = make_uint4(0, 0, 0, 0);
    // fully coalesced: 64 lanes = 8 complete rows (1 KB)
    *(uint4*)&aggh[(size_t)(nb + nl) * DD + c8] = acc;
}

// ---------------- dense update via MFMA ----------------
__global__ __launch_bounds__(256, 4) void layer_mfma_kernel(
        const __half* __restrict__ aggh,
        __half* __restrict__ hh,
        float* __restrict__ hout,
        const float* __restrict__ Wl,
        const float* __restrict__ bl,
        const float* __restrict__ Wr,
        int last) {
    __shared__ char smem[2 * MB2 * APAD * 2];   // 34816 B, reused by epilogue
    _Float16* a_s  = (_Float16*)smem;                          // [64][APAD]
    _Float16* bt_s = (_Float16*)(smem + MB2 * APAD * 2);       // [64][APAD], n-major

    int tid = threadIdx.x;
    int lane = tid & 63;
    int w = tid >> 6;
    int node0 = blockIdx.x * MB2;

    #pragma unroll
    for (int i = 0; i < 4; ++i) {
        int idx = i * 256 + tid;          // uint4 id, 1024 total
        int r = idx >> 4;
        int c4 = idx & 15;
        int node = node0 + r; if (node > NN - 1) node = NN - 1;
        const __half* srcp = (c4 < 8) ? (aggh + (size_t)node * DD + c4 * 8)
                                      : (hh + (size_t)node * DD + (c4 - 8) * 8);
        uint4 v = *(const uint4*)srcp;
        *(uint4*)&a_s[r * APAD + c4 * 8] = v;
    }
    {
        int n = tid & 63;
        int kb = tid >> 6;
        #pragma unroll
        for (int kk = 0; kk < 32; ++kk) {
            int k = kb * 32 + kk;
            float wv = (k < 64) ? Wl[k * DD + n] : Wr[(k - 64) * DD + n];
            bt_s[n * APAD + k] = (_Float16)wv;
        }
    }
    __syncthreads();

    floatx4 acc[4];
    #pragma unroll
    for (int nt = 0; nt < 4; ++nt) acc[nt] = (floatx4){0.f, 0.f, 0.f, 0.f};
    int m = lane & 15;
    int q = lane >> 4;

    #pragma unroll
    for (int ks = 0; ks < 4; ++ks) {
        half8 af = *(half8*)&a_s[(w * 16 + m) * APAD + q * 8 + ks * 32];
        #pragma unroll
        for (int nt = 0; nt < 4; ++nt) {
            half8 bf = *(half8*)&bt_s[(nt * 16 + m) * APAD + q * 8 + ks * 32];
            acc[nt] = __builtin_amdgcn_mfma_f32_16x16x32_f16(af, bf, acc[nt], 0, 0, 0);
        }
    }
    __syncthreads();

    _Float16* ch = (_Float16*)smem;                      // [64][CPADH]
    float*    cf = (float*)(smem + MB2 * CPADH * 2);     // [64][CPADF]

    #pragma unroll
    for (int nt = 0; nt < 4; ++nt) {
        int col = nt * 16 + m;
        float b = bl[col];
        #pragma unroll
        for (int r = 0; r < 4; ++r) {
            int rowl = w * 16 + q * 4 + r;
            float o = fmaxf(acc[nt][r] + b, 0.0f);
            if (last) cf[rowl * CPADF + col] = o;
            else      ch[rowl * CPADH + col] = (_Float16)o;
        }
    }
    __syncthreads();

    if (!last) {
        #pragma unroll
        for (int i = 0; i < 2; ++i) {
            int idx = i * 256 + tid;          // 512 uint4s
            int r = idx >> 3;
            int c4 = idx & 7;
            int node = node0 + r;
            if (node < NN) {
                uint4 v = *(uint4*)&ch[r * CPADH + c4 * 8];
                *(uint4*)&hh[(size_t)node * DD + c4 * 8] = v;
            }
        }
    } else {
        #pragma unroll
        for (int i = 0; i < 4; ++i) {
            int idx = i * 256 + tid;      // 1024 float4s
            int r = idx >> 4;
            int c4 = idx & 15;
            int node = node0 + r;
            if (node < NN) {
                float4 v = *(float4*)&cf[r * CPADF + c4 * 4];
                *(float4*)&hout[(size_t)node * DD + c4 * 4] = v;
            }
        }
    }
}

extern "C" void kernel_launch(void* const* d_in, const int* in_sizes, int n_in,
                              void* d_out, int out_size, void* d_ws, size_t ws_size,
                              hipStream_t stream) {
    const float* x  = (const float*)d_in[0];
    const int*   ei = (const int*)d_in[1];
    const float* Wl = (const float*)d_in[2];
    const float* bl = (const float*)d_in[3];
    const float* Wr = (const float*)d_in[4];
    float* h = (float*)d_out;

    const int* src = ei;
    const int* dst = ei + NE;

    char* ws = (char*)d_ws;
    __half* aggh     = (__half*)ws;  ws += (size_t)NN * DD * sizeof(__half);  // 12.8 MB
    __half* hh       = (__half*)ws;  ws += (size_t)NN * DD * sizeof(__half);  // 12.8 MB
    int* row_start   = (int*)ws;     ws += (size_t)(NN + 16) * sizeof(int);
    int* blockcnt    = (int*)ws;     ws += (size_t)(SCANA_N + 16) * sizeof(int);
    int* rowsum      = (int*)ws;     ws += (size_t)(NPART3 + 16) * sizeof(int);
    int* csr         = (int*)ws;                                              // 5 MB

    // packed edge bucket reuses the aggh region (dead until first agg_kernel)
    int* ebufP = (int*)aggh;                     // NE ints = 5 MB <= 12.8 MB

    cast_kernel<<<(NN * DD / 4) / 256, 256, 0, stream>>>(x, hh);

    countA_kernel<<<NTB, 256, 0, stream>>>(dst, blockcnt);
    scanP1_kernel<<<NPART3, 512, 0, stream>>>(blockcnt, rowsum);
    scanP2_kernel<<<1, 256, 0, stream>>>(rowsum);
    scatterA_kernel<<<NTB, 256, 0, stream>>>(src, dst, blockcnt, rowsum, ebufP);
    fillD_kernel<<<NPART3, 1024, 0, stream>>>(ebufP, rowsum, row_start, csr);

    for (int l = 0; l < NL; ++l) {
        agg_kernel<<<NN / 32, 256, 0, stream>>>(hh, row_start, csr, aggh);
        layer_mfma_kernel<<<L2BLOCKS, 256, 0, stream>>>(
            aggh, hh, h, Wl + (size_t)l * DD * DD, bl + (size_t)l * DD, Wr + (size_t)l * DD * DD,
            (l == NL - 1) ? 1 : 0);
    }
}